// Round 12
// baseline (59.280 us; speedup 1.0000x reference)
//
#include <hip/hip_runtime.h>

#define CC 64
#define TT 8192
#define NB 8
#define NW16 32768          // 16-t windows: 64 b * 512
#define GRID 768            // 3 blocks/CU resident (4 waves each = 12 waves/CU)
#define NWAVES (GRID * 4)   // 3072 waves; ~10.7 windows each

typedef __attribute__((ext_vector_type(8))) short bf16x8;
typedef __attribute__((ext_vector_type(4))) float f32x4;
typedef __attribute__((ext_vector_type(4))) int i32x4;

union I4B8 { i32x4 i; bf16x8 b; };

__device__ __forceinline__ unsigned short f32_to_bf16_rn(float f) {
    unsigned u = __float_as_uint(f);
    unsigned r = (u + 0x7FFFu + ((u >> 16) & 1u)) >> 16;
    return (unsigned short)r;
}
__device__ __forceinline__ float bf16_to_f32(unsigned short h) {
    return __uint_as_float(((unsigned)h) << 16);
}

// ---- prep: Wf hi/lo interleaved, MFMA A-fragment order ----------------------
// slot = ((mt*2+ks)*2+h)*64 + lane ; Wf[slot*8 + j] = W_h[p][c]
//   p = mt*16 + (lane&15), c = ks*32 + (lane>>4)*8 + j
//   p<32: scaled E (r=p>>3, n=p&7) ; p>=32: F ; h=0 hi(rn), h=1 lo(rn resid)
__global__ __launch_bounds__(256) void rpg_prep(
    const float* __restrict__ sigma, const float* __restrict__ rho,
    const float* __restrict__ E, const float* __restrict__ F,
    unsigned short* __restrict__ Wf)
{
    const int idx = blockIdx.x * 256 + threadIdx.x;
    if (idx >= 8192) return;
    const int j    = idx & 7;
    const int slot = idx >> 3;
    const int lane = slot & 63;
    const int h    = (slot >> 6) & 1;
    const int ks   = (slot >> 7) & 1;
    const int mt   = (slot >> 8) & 3;
    const int p = mt * 16 + (lane & 15);
    const int c = ks * 32 + (lane >> 4) * 8 + j;
    float val;
    if (p < 32) {
        const int r = p >> 3, n = p & 7;
        const float es = 8.0f / (1e-5f + fabsf(sigma[r]));
        const float fs = 8.0f / (1e-5f + fabsf(rho[r]));
        val = E[r * (CC * NB) + c * NB + n] * (es * fs * 0.25f);
    } else {
        const int r = (p - 32) >> 3, n = p & 7;
        val = F[r * (CC * NB) + c * NB + n];
    }
    const unsigned short hi = f32_to_bf16_rn(val);
    Wf[idx] = (h == 0) ? hi : f32_to_bf16_rn(val - bf16_to_f32(hi));
}

// ---- main: persistent, zero LDS, zero barriers, 3-pass hi/lo MFMA -----------
// wave = one 16-t window per iteration, all 64 output rows.
__global__ __launch_bounds__(256, 3) void rpg_main(
    const float* __restrict__ x,
    const unsigned short* __restrict__ Wf,
    float* __restrict__ out)
{
    const int tid  = threadIdx.x;
    const int w    = tid >> 6;
    const int lane = tid & 63;
    const int am   = lane & 15;      // t within window; MFMA B/D col
    const int ag   = lane >> 4;      // k-group

    // ---- W hi/lo fragments -> VGPRs (once; coalesced, L2-served) ------------
    bf16x8 wfh[8], wfl[8];
    #pragma unroll
    for (int s = 0; s < 8; ++s) {
        wfh[s] = *(const bf16x8*)(Wf + ((s * 2 + 0) * 64 + lane) * 8);
        wfl[s] = *(const bf16x8*)(Wf + ((s * 2 + 1) * 64 + lane) * 8);
    }

    const bool ra0 = (ag & 2) == 0;
    const bool qlo = (ag & 1) == 0;

    int wid = blockIdx.x * 4 + w;

    // ---- prefetch window 0 into f (fragment-ordered global loads) -----------
    float f[16];
    {
        const int b = wid >> 9, t0 = (wid & 511) << 4;
        const float* xp = x + b * (CC * TT) + t0 + am;
        #pragma unroll
        for (int k = 0; k < 16; ++k) {
            const int c = ((k >> 3) * 32) + ag * 8 + (k & 7);
            f[k] = xp[c * TT];
        }
    }

    #pragma unroll 1
    while (wid < NW16) {
        // ---- convert f -> bf16 hi/lo B-frags (in registers) -----------------
        bf16x8 xh[2], xl[2];
        #pragma unroll
        for (int ks = 0; ks < 2; ++ks) {
            unsigned hw[4], lw[4];
            #pragma unroll
            for (int k = 0; k < 4; ++k) {
                const float f0 = f[ks * 8 + 2 * k];
                const float f1 = f[ks * 8 + 2 * k + 1];
                const unsigned u0 = __float_as_uint(f0), u1 = __float_as_uint(f1);
                hw[k] = (u0 >> 16) | (u1 & 0xFFFF0000u);
                const float h0 = __uint_as_float(u0 & 0xFFFF0000u);
                const float h1 = __uint_as_float(u1 & 0xFFFF0000u);
                lw[k] = (__float_as_uint(f0 - h0) >> 16) |
                        (__float_as_uint(f1 - h1) & 0xFFFF0000u);
            }
            I4B8 H, L;
            H.i = (i32x4){(int)hw[0], (int)hw[1], (int)hw[2], (int)hw[3]};
            L.i = (i32x4){(int)lw[0], (int)lw[1], (int)lw[2], (int)lw[3]};
            xh[ks] = H.b;
            xl[ks] = L.b;
        }

        const int b  = wid >> 9;
        const int t0 = (wid & 511) << 4;
        const int nxt = wid + NWAVES;

        // ---- prefetch next window (flies under MFMA + epilogue) -------------
        if (nxt < NW16) {
            const int nb = nxt >> 9, nt0 = (nxt & 511) << 4;
            const float* xp = x + nb * (CC * TT) + nt0 + am;
            #pragma unroll
            for (int k = 0; k < 16; ++k) {
                const int c = ((k >> 3) * 32) + ag * 8 + (k & 7);
                f[k] = xp[c * TT];
            }
        }

        // ---- GEMM: acc[mt][i] = Y[p = mt*16 + ag*4 + i][t0 + am], 3-pass ----
        f32x4 acc[4];
        #pragma unroll
        for (int mt = 0; mt < 4; ++mt) {
            acc[mt] = (f32x4){0.0f, 0.0f, 0.0f, 0.0f};
            #pragma unroll
            for (int ks = 0; ks < 2; ++ks) {
                const bf16x8 wh = wfh[mt * 2 + ks];
                const bf16x8 wl = wfl[mt * 2 + ks];
                acc[mt] = __builtin_amdgcn_mfma_f32_16x16x32_bf16(wh, xh[ks], acc[mt], 0, 0, 0);
                acc[mt] = __builtin_amdgcn_mfma_f32_16x16x32_bf16(wh, xl[ks], acc[mt], 0, 0, 0);
                acc[mt] = __builtin_amdgcn_mfma_f32_16x16x32_bf16(wl, xh[ks], acc[mt], 0, 0, 0);
            }
        }

        // ---- in-register epilogue (verified lane algebra) -------------------
        float pA[4], pB[4], pC[4], pD[4];
        #pragma unroll
        for (int i = 0; i < 4; ++i) {
            pA[i] = __shfl_xor(acc[0][i], 32);
            pB[i] = __shfl_xor(acc[1][i], 32);
            pC[i] = __shfl_xor(acc[2][i], 32);
            pD[i] = __shfl_xor(acc[3][i], 32);
        }

        float xe_[4][2];
        #pragma unroll
        for (int e = 0; e < 2; ++e) {
            xe_[0][e] = ra0 ? acc[0][e] : pA[2 + e];
            xe_[1][e] = ra0 ? pA[e]     : acc[0][2 + e];
            xe_[2][e] = ra0 ? acc[1][e] : pB[2 + e];
            xe_[3][e] = ra0 ? pB[e]     : acc[1][2 + e];
        }

        float xfq0[4], xfq1[4], xfq2[4], xfq3[4];
        #pragma unroll
        for (int i = 0; i < 4; ++i) {
            xfq0[i] = ra0 ? acc[2][i] : pC[i];
            xfq1[i] = ra0 ? pC[i]     : acc[2][i];
            xfq2[i] = ra0 ? acc[3][i] : pD[i];
            xfq3[i] = ra0 ? pD[i]     : acc[3][i];
        }
        float xfo0[4], xfo1[4], xfo2[4], xfo3[4];
        #pragma unroll
        for (int i = 0; i < 4; ++i) {
            xfo0[i] = __shfl_xor(xfq0[i], 16);
            xfo1[i] = __shfl_xor(xfq1[i], 16);
            xfo2[i] = __shfl_xor(xfq2[i], 16);
            xfo3[i] = __shfl_xor(xfq3[i], 16);
        }
        float xfL[4][4], xfH[4][4];
        #pragma unroll
        for (int i = 0; i < 4; ++i) {
            xfL[0][i] = qlo ? xfq0[i] : xfo0[i];  xfH[0][i] = qlo ? xfo0[i] : xfq0[i];
            xfL[1][i] = qlo ? xfq1[i] : xfo1[i];  xfH[1][i] = qlo ? xfo1[i] : xfq1[i];
            xfL[2][i] = qlo ? xfq2[i] : xfo2[i];  xfH[2][i] = qlo ? xfo2[i] : xfq2[i];
            xfL[3][i] = qlo ? xfq3[i] : xfo3[i];  xfH[3][i] = qlo ? xfo3[i] : xfq3[i];
        }

        float z[2][8];
        float pm = 0.0f;
        #pragma unroll
        for (int e = 0; e < 2; ++e) {
            #pragma unroll
            for (int m = 0; m < 4; ++m) {
                float a = xe_[0][e] * xfL[0][m];
                a = fmaf(xe_[1][e], xfL[1][m], a);
                a = fmaf(xe_[2][e], xfL[2][m], a);
                a = fmaf(xe_[3][e], xfL[3][m], a);
                float s = __builtin_amdgcn_sqrtf(fabsf(a) + 0.01f) - 0.1f;
                float v = copysignf(s, a);
                z[e][m] = v;
                pm = fmaxf(pm, fabsf(v));
            }
            #pragma unroll
            for (int m = 0; m < 4; ++m) {
                float a = xe_[0][e] * xfH[0][m];
                a = fmaf(xe_[1][e], xfH[1][m], a);
                a = fmaf(xe_[2][e], xfH[2][m], a);
                a = fmaf(xe_[3][e], xfH[3][m], a);
                float s = __builtin_amdgcn_sqrtf(fabsf(a) + 0.01f) - 0.1f;
                float v = copysignf(s, a);
                z[e][4 + m] = v;
                pm = fmaxf(pm, fabsf(v));
            }
        }

        pm = fmaxf(pm, __shfl_xor(pm, 16));
        pm = fmaxf(pm, __shfl_xor(pm, 32));
        const float rinv = __builtin_amdgcn_rcpf(pm + 1e-5f);

        const int nbase = (qlo ? 0 : 4) + (ra0 ? 0 : 2);
        float* ob = out + b * (64 * TT) + t0 + am;
        #pragma unroll
        for (int e = 0; e < 2; ++e)
            #pragma unroll
            for (int m = 0; m < 8; ++m)
                ob[((nbase + e) * NB + m) * TT] = z[e][m] * rinv;

        wid = nxt;
    }
}

extern "C" void kernel_launch(void* const* d_in, const int* in_sizes, int n_in,
                              void* d_out, int out_size, void* d_ws, size_t ws_size,
                              hipStream_t stream) {
    const float* x     = (const float*)d_in[0];
    const float* sigma = (const float*)d_in[1];
    const float* rho   = (const float*)d_in[2];
    const float* E     = (const float*)d_in[3];
    const float* F     = (const float*)d_in[4];
    float* out = (float*)d_out;

    unsigned short* Wf = (unsigned short*)d_ws;   // 8192 shorts = 16 KB

    rpg_prep<<<32, 256, 0, stream>>>(sigma, rho, E, F, Wf);

    rpg_main<<<GRID, 256, 0, stream>>>(x, Wf, out);
}